// Round 5
// baseline (153.520 us; speedup 1.0000x reference)
//
#include <hip/hip_runtime.h>
#include <math.h>

#define H 512
#define W 512
#define HW (H * W)
#define NCH 6

__device__ __forceinline__ int reflect_idx(int p, int n) {
    if (p < 0) p = -p;
    if (p >= n) p = 2 * n - 2 - p;
    return p;
}

// ---------------- K1: Sobel (LDS-tiled, 128x8, 4 px/thread interleaved) ----------------
// cmax (per-channel img max) dropped: pipeline is scale-invariant past the clamp;
// cmax only rescales the 1e-12 clamp threshold (~1e-6 effect). Sobel on RAW img.
__global__ __launch_bounds__(256) void k_sobel(const float* __restrict__ img,
                                               float* __restrict__ gpart,
                                               float* __restrict__ g,
                                               float* __restrict__ xn,
                                               float* __restrict__ yn) {
    const int SW = 132, SH = 10;
    __shared__ float st[SH * SW];

    int ch = blockIdx.z;
    int bx0 = blockIdx.x * 128, by0 = blockIdx.y * 8;
    int tx = threadIdx.x, ty = threadIdx.y;
    int tid = ty * 32 + tx;
    const float* im = img + (size_t)ch * HW;

    for (int i = tid; i < SH * 130; i += 256) {
        int r = i / 130, c = i - r * 130;
        int yy = by0 - 1 + r, xx = bx0 - 1 + c;
        float v = 0.f;
        if (yy >= 0 && yy < H && xx >= 0 && xx < W) v = im[yy * W + xx];  // zero pad
        st[r * SW + c] = v;
    }
    __syncthreads();

    float bmax = 0.f;
    int y = by0 + ty;
    int r = ty + 1;
    float gm4[4], xr4[4], yr4[4];
#pragma unroll
    for (int k = 0; k < 4; ++k) {
        int c = tx + 32 * k + 1;
        float a00 = st[(r - 1) * SW + c - 1], a01 = st[(r - 1) * SW + c], a02 = st[(r - 1) * SW + c + 1];
        float a10 = st[r * SW + c - 1], a12 = st[r * SW + c + 1];
        float a20 = st[(r + 1) * SW + c - 1], a21 = st[(r + 1) * SW + c], a22 = st[(r + 1) * SW + c + 1];

        float gx = (a02 - a00) + 2.f * (a12 - a10) + (a22 - a20);
        float gy = (a20 - a00) + 2.f * (a21 - a01) + (a22 - a02);

        gx = fmaxf(gx, 1e-12f);
        gy = fmaxf(gy, 1e-12f);
        float d = gx * gx + gy * gy;
        float rq = __builtin_amdgcn_rsqf(d);
        float gm = d * rq;
        float xv = gx * rq, yv = gy * rq;
        const float ct = -4.37113883e-08f;  // cosf(fp32 pi/2); sin = 1.0 exactly
        gm4[k] = gm;
        xr4[k] = xv * ct - yv;
        yr4[k] = yv * ct + xv;
        bmax = fmaxf(bmax, gm);
    }
#pragma unroll
    for (int k = 0; k < 4; ++k) {
        int idx = y * W + bx0 + tx + 32 * k;
        float* gc = g + (size_t)ch * HW;
        float* xc = xn + (size_t)ch * HW;
        float* yc = yn + (size_t)ch * HW;
        gc[idx] = gm4[k];
        xc[idx] = xr4[k];
        yc[idx] = yr4[k];
    }

    __syncthreads();
    st[tid] = bmax;
    __syncthreads();
    for (int s = 128; s > 0; s >>= 1) {
        if (tid < s) st[tid] = fmaxf(st[tid], st[tid + s]);
        __syncthreads();
    }
    if (tid == 0) gpart[ch * 256 + blockIdx.y * 4 + blockIdx.x] = st[0];
}

// ---------------- fused 3-iteration ETF ----------------
#define ST 80   // LDS row stride (floats)
#define SR 28   // staged rows (halo 6)
#define SC 76   // staged cols (halo 6)

template <int OFF>
__device__ __forceinline__ void ldrow(const float* p, float* w) {
    const float4* q = (const float4*)p;
    float4 a = q[0], b = q[1];
    if (OFF == 0) {
        w[0] = a.x; w[1] = a.y; w[2] = a.z; w[3] = a.w;
        w[4] = b.x; w[5] = b.y; w[6] = b.z; w[7] = b.w;
    } else {  // OFF == 2
        float4 c = q[2];
        w[0] = a.z; w[1] = a.w; w[2] = b.x; w[3] = b.y;
        w[4] = b.z; w[5] = b.w; w[6] = c.x; w[7] = c.y;
    }
}

// Compute one 4-px group's smoothed (unnormalized) xr/yr from LDS.
template <int OFF>
__device__ __forceinline__ void etf_group(const float* sg, const float* se,
                                          const float* sx, const float* sy,
                                          int row, int ab, float* xr, float* yr) {
    float cxw[8], cyw[8], cew[8];
    ldrow<OFF>(sx + row * ST + ab, cxw);
    ldrow<OFF>(sy + row * ST + ab, cyw);
    ldrow<OFF>(se + row * ST + ab, cew);
    float cx[4], cy[4], ec[4];
#pragma unroll
    for (int k = 0; k < 4; ++k) {
        cx[k] = cxw[k + 2];
        cy[k] = cyw[k + 2];
        ec[k] = __builtin_amdgcn_rcpf(cew[k + 2]);  // e^{+2 cg/gmax}
    }
#pragma unroll
    for (int k = 0; k < 4; ++k) { xr[k] = 0.f; yr[k] = 0.f; }
#pragma unroll
    for (int dy = -2; dy <= 2; ++dy) {
        float gw[8], xw[8], yw[8], ew[8];
        const int rb = (row + dy) * ST + ab;
        ldrow<OFF>(sg + rb, gw);
        ldrow<OFF>(sx + rb, xw);
        ldrow<OFF>(sy + rb, yw);
        ldrow<OFF>(se + rb, ew);
#pragma unroll
        for (int k = 0; k < 4; ++k) {
#pragma unroll
            for (int dxi = 0; dxi < 5; ++dxi) {
                int n = k + dxi;
                float dot = cx[k] * xw[n] + cy[k] * yw[n];
                float wm = __builtin_amdgcn_rcpf(1.f + ew[n] * ec[k]);
                float m = gw[n] * (wm * dot);
                xr[k] = fmaf(m, xw[n], xr[k]);
                yr[k] = fmaf(m, yw[n], yr[k]);
            }
        }
    }
}

// Non-final phase: compute region [X0,X0+WW)x[Y0,Y0+HH) in staged coords,
// hold results in regs, barrier, write back into sx/sy in place.
template <int X0, int Y0, int WW, int HH>
__device__ __forceinline__ void run_phase(const float* sg, const float* se,
                                          float* sx, float* sy, int tid) {
    constexpr int W4 = WW / 4;
    constexpr int SB = ((X0 - 2) / 4) * 4;
    constexpr int OFF = (X0 - 2) - SB;
    constexpr int NG = W4 * HH;
    float ox[2][4], oy[2][4];
    int ng = 0;
    for (int gi = tid; gi < NG; gi += 256, ++ng) {
        int gm = gi % W4, gr = gi / W4;
        int row = Y0 + gr;
        int ab = SB + 4 * gm;
        float xr[4], yr[4];
        etf_group<OFF>(sg, se, sx, sy, row, ab, xr, yr);
#pragma unroll
        for (int k = 0; k < 4; ++k) {
            float im2 = __builtin_amdgcn_rsqf(xr[k] * xr[k] + yr[k] * yr[k]);
            ox[ng][k] = xr[k] * im2;
            oy[ng][k] = yr[k] * im2;
        }
    }
    __syncthreads();
    ng = 0;
    for (int gi = tid; gi < NG; gi += 256, ++ng) {
        int gm = gi % W4, gr = gi / W4;
        int c0 = (Y0 + gr) * ST + X0 + 4 * gm;
        *(float2*)&sx[c0] = make_float2(ox[ng][0], ox[ng][1]);
        *(float2*)&sx[c0 + 2] = make_float2(ox[ng][2], ox[ng][3]);
        *(float2*)&sy[c0] = make_float2(oy[ng][0], oy[ng][1]);
        *(float2*)&sy[c0 + 2] = make_float2(oy[ng][2], oy[ng][3]);
    }
    __syncthreads();
}

// K2: all 3 ETF iterations in LDS. Tile 64x16 output, halo 6 staged (reflect).
// Reflection commutes with the value-weighted 5x5 sum, so virtual-coord iteration
// is exact. g (and se=exp(-2g/gmax)) are iteration-invariant.
__global__ __launch_bounds__(256) void k_fused3(const float* __restrict__ g,
                                                const float* __restrict__ xin,
                                                const float* __restrict__ yin,
                                                const float* __restrict__ gpart,
                                                float* __restrict__ out,
                                                double* __restrict__ partials) {
    __shared__ __align__(16) float sg[SR * ST];
    __shared__ __align__(16) float se[SR * ST];
    __shared__ __align__(16) float sx[SR * ST];
    __shared__ __align__(16) float sy[SR * ST];
    __shared__ float smax;
    __shared__ double rs[256], rq[256];

    int ch = blockIdx.z;
    int bx0 = blockIdx.x * 64, by0 = blockIdx.y * 16;
    int tid = threadIdx.x;

    // wave 0: reduce this channel's 256 sobel-block maxima -> smax
    if (tid < 64) {
        const float* gp = gpart + ch * 256;
        float m = fmaxf(fmaxf(gp[tid], gp[tid + 64]), fmaxf(gp[tid + 128], gp[tid + 192]));
#pragma unroll
        for (int k = 32; k > 0; k >>= 1) m = fmaxf(m, __shfl_xor(m, k, 64));
        if (tid == 0) smax = m;
    }

    // stage g/x/y with reflect halo 6; keep g in regs for the exp phase
    const float* gc = g + (size_t)ch * HW;
    const float* xc = xin + (size_t)ch * HW;
    const float* yc = yin + (size_t)ch * HW;
    float vg[9];
    int nj = 0;
    for (int i = tid; i < SR * SC; i += 256, ++nj) {
        int r = i / SC, c = i - r * SC;
        int yy = reflect_idx(by0 - 6 + r, H);
        int xx = reflect_idx(bx0 - 6 + c, W);
        int idx = yy * W + xx;
        int s = r * ST + c;
        float gv = gc[idx];
        vg[nj] = gv;
        sg[s] = gv;
        sx[s] = xc[idx];
        sy[s] = yc[idx];
    }
    __syncthreads();

    float s2 = -2.f * __builtin_amdgcn_rcpf(smax);  // sigmoid(2d/gmax) = 0.5(1+tanh(d/gmax))
    nj = 0;
    for (int i = tid; i < SR * SC; i += 256, ++nj) {
        int r = i / SC, c = i - r * SC;
        se[r * ST + c] = __expf(s2 * vg[nj]);
    }
    __syncthreads();

    // iterations 1 and 2 (in-place x/y update, register round-trip)
    run_phase<2, 2, 72, 24>(sg, se, sx, sy, tid);
    run_phase<4, 4, 68, 20>(sg, se, sx, sy, tid);

    // iteration 3 fused with angle + instance-norm partials; 1 group/thread
    {
        int gm = tid & 15, gr = tid >> 4;
        int row = 6 + gr;
        int ab = 4 + 4 * gm;  // SB=4, OFF=0 for X0=6
        float xr[4], yr[4];
        etf_group<0>(sg, se, sx, sy, row, ab, xr, yr);

        float a[4];
        double s = 0.0, q = 0.0;
#pragma unroll
        for (int k = 0; k < 4; ++k) {
            float ang = atanf(-yr[k] / xr[k]);  // normalization cancels in the ratio
            a[k] = (180.f * ang) / 3.14159274f;
            s += (double)a[k];
            q += (double)a[k] * (double)a[k];
        }
        float* oc = out + (size_t)ch * HW;
        *(float4*)(oc + (by0 + gr) * W + bx0 + 4 * gm) = make_float4(a[0], a[1], a[2], a[3]);

        rs[tid] = s;
        rq[tid] = q;
    }
    __syncthreads();
    for (int st = 128; st > 0; st >>= 1) {
        if (tid < st) {
            rs[tid] += rs[tid + st];
            rq[tid] += rq[tid + st];
        }
        __syncthreads();
    }
    if (tid == 0) {
        int blk = blockIdx.y * 8 + blockIdx.x;  // 256 blocks per channel
        partials[((size_t)ch * 256 + blk) * 2 + 0] = rs[0];
        partials[((size_t)ch * 256 + blk) * 2 + 1] = rq[0];
    }
}

// ---------------- K3: instance norm (inline stats reduce, then normalize) ----------------
__global__ __launch_bounds__(256) void k_norm(float* __restrict__ a,
                                              const double* __restrict__ partials) {
    int ch = blockIdx.y;
    int t = threadIdx.x;

    __shared__ double rs[256], rq[256];
    rs[t] = partials[((size_t)ch * 256 + t) * 2 + 0];
    rq[t] = partials[((size_t)ch * 256 + t) * 2 + 1];
    __syncthreads();
    for (int st = 128; st > 0; st >>= 1) {
        if (t < st) {
            rs[t] += rs[t + st];
            rq[t] += rq[t + st];
        }
        __syncthreads();
    }
    __shared__ float sm, ss;
    if (t == 0) {
        double mean = rs[0] / (double)HW;
        double var = rq[0] / (double)HW - mean * mean;
        sm = (float)mean;
        ss = (float)(1.0 / sqrt(var + 1e-5));
    }
    __syncthreads();
    float mean = sm, sc = ss;

    float4* a4 = (float4*)(a + (size_t)ch * HW + (size_t)blockIdx.x * 4096);
#pragma unroll
    for (int k = 0; k < 4; ++k) {
        float4 v = a4[k * 256 + t];
        v.x = (v.x - mean) * sc;
        v.y = (v.y - mean) * sc;
        v.z = (v.z - mean) * sc;
        v.w = (v.w - mean) * sc;
        a4[k * 256 + t] = v;
    }
}

extern "C" void kernel_launch(void* const* d_in, const int* in_sizes, int n_in,
                              void* d_out, int out_size, void* d_ws, size_t ws_size,
                              hipStream_t stream) {
    (void)in_sizes; (void)n_in; (void)out_size; (void)ws_size;
    const float* img = (const float*)d_in[0];
    float* out = (float*)d_out;

    float* wsf = (float*)d_ws;
    float* gpart = wsf + 512;                       // 6*256
    double* partials = (double*)(wsf + 8192);       // 6*256*2 doubles
    float* g = wsf + 32768;                         // 3 fields of 6 MiB
    float* xnA = g + (size_t)NCH * HW;
    float* ynA = xnA + (size_t)NCH * HW;

    k_sobel<<<dim3(4, 64, NCH), dim3(32, 8), 0, stream>>>(img, gpart, g, xnA, ynA);
    k_fused3<<<dim3(8, 32, NCH), dim3(256), 0, stream>>>(g, xnA, ynA, gpart, out, partials);
    k_norm<<<dim3(64, NCH), dim3(256), 0, stream>>>(out, partials);
}

// Round 6
// 152.798 us; speedup vs baseline: 1.0047x; 1.0047x over previous
//
#include <hip/hip_runtime.h>
#include <math.h>

#define H 512
#define W 512
#define HW (H * W)
#define NCH 6

__device__ __forceinline__ int reflect_idx(int p, int n) {
    if (p < 0) p = -p;
    if (p >= n) p = 2 * n - 2 - p;
    return p;
}

// ---------------- K1: Sobel (LDS-tiled, 128x8, 4 px/thread interleaved) ----------------
__global__ __launch_bounds__(256) void k_sobel(const float* __restrict__ img,
                                               float* __restrict__ gpart,
                                               float* __restrict__ g,
                                               float* __restrict__ xn,
                                               float* __restrict__ yn) {
    const int SW = 132, SH = 10;
    __shared__ float st[SH * SW];

    int ch = blockIdx.z;
    int bx0 = blockIdx.x * 128, by0 = blockIdx.y * 8;
    int tx = threadIdx.x, ty = threadIdx.y;
    int tid = ty * 32 + tx;
    const float* im = img + (size_t)ch * HW;

    for (int i = tid; i < SH * 130; i += 256) {
        int r = i / 130, c = i - r * 130;
        int yy = by0 - 1 + r, xx = bx0 - 1 + c;
        float v = 0.f;
        if (yy >= 0 && yy < H && xx >= 0 && xx < W) v = im[yy * W + xx];  // zero pad
        st[r * SW + c] = v;
    }
    __syncthreads();

    float bmax = 0.f;
    int y = by0 + ty;
    int r = ty + 1;
    float gm4[4], xr4[4], yr4[4];
#pragma unroll
    for (int k = 0; k < 4; ++k) {
        int c = tx + 32 * k + 1;
        float a00 = st[(r - 1) * SW + c - 1], a01 = st[(r - 1) * SW + c], a02 = st[(r - 1) * SW + c + 1];
        float a10 = st[r * SW + c - 1], a12 = st[r * SW + c + 1];
        float a20 = st[(r + 1) * SW + c - 1], a21 = st[(r + 1) * SW + c], a22 = st[(r + 1) * SW + c + 1];

        float gx = (a02 - a00) + 2.f * (a12 - a10) + (a22 - a20);
        float gy = (a20 - a00) + 2.f * (a21 - a01) + (a22 - a02);

        gx = fmaxf(gx, 1e-12f);
        gy = fmaxf(gy, 1e-12f);
        float d = gx * gx + gy * gy;
        float rq = __builtin_amdgcn_rsqf(d);
        float gm = d * rq;
        float xv = gx * rq, yv = gy * rq;
        const float ct = -4.37113883e-08f;  // cosf(fp32 pi/2); sin = 1.0 exactly
        gm4[k] = gm;
        xr4[k] = xv * ct - yv;
        yr4[k] = yv * ct + xv;
        bmax = fmaxf(bmax, gm);
    }
#pragma unroll
    for (int k = 0; k < 4; ++k) {
        int idx = y * W + bx0 + tx + 32 * k;
        float* gc = g + (size_t)ch * HW;
        float* xc = xn + (size_t)ch * HW;
        float* yc = yn + (size_t)ch * HW;
        gc[idx] = gm4[k];
        xc[idx] = xr4[k];
        yc[idx] = yr4[k];
    }

    __syncthreads();
    st[tid] = bmax;
    __syncthreads();
    for (int s = 128; s > 0; s >>= 1) {
        if (tid < s) st[tid] = fmaxf(st[tid], st[tid + s]);
        __syncthreads();
    }
    if (tid == 0) gpart[ch * 256 + blockIdx.y * 4 + blockIdx.x] = st[0];
}

// ---------------- fused 3-iteration ETF ----------------
#define ST 76       // LDS row stride = staged cols (16B-aligned rows: 76*4=304B)
#define SRR 28      // staged rows (halo 6)
#define NSTAGE (SRR * ST)  // 2128

struct Row { float g[8], x[8], y[8], e[8]; };

__device__ __forceinline__ void ldrow8(const float* p, float* w) {
    const float4* q = (const float4*)p;
    float4 a = q[0], b = q[1];
    w[0] = a.x; w[1] = a.y; w[2] = a.z; w[3] = a.w;
    w[4] = b.x; w[5] = b.y; w[6] = b.z; w[7] = b.w;
}

__device__ __forceinline__ void load_row(const float* sg, const float* se,
                                         const float* sx, const float* sy,
                                         int base, Row& r) {
    ldrow8(sg + base, r.g);
    ldrow8(sx + base, r.x);
    ldrow8(sy + base, r.y);
    ldrow8(se + base, r.e);
}

__device__ __forceinline__ void extract_center(const Row& r, float* cx, float* cy, float* ec) {
#pragma unroll
    for (int k = 0; k < 4; ++k) {
        cx[k] = r.x[k + 2];
        cy[k] = r.y[k + 2];
        ec[k] = __builtin_amdgcn_rcpf(r.e[k + 2]);  // e^{+2 g_c/gmax}
    }
}

// one loaded row's contribution to 4 center pixels
__device__ __forceinline__ void contrib(const Row& rw, const float* cx, const float* cy,
                                        const float* ec, float* xr, float* yr) {
#pragma unroll
    for (int k = 0; k < 4; ++k) {
#pragma unroll
        for (int d = 0; d < 5; ++d) {
            int n = k + d;
            float dot = cx[k] * rw.x[n] + cy[k] * rw.y[n];
            float wm = __builtin_amdgcn_rcpf(1.f + rw.e[n] * ec[k]);
            float m = rw.g[n] * (wm * dot);
            xr[k] = fmaf(m, rw.x[n], xr[k]);
            yr[k] = fmaf(m, rw.y[n], yr[k]);
        }
    }
}

// Phase over 2-row units: centers cols [2,74) (18 groups, windows [0,8)+4gm all
// 16B-aligned), rows [Y0, Y0+NROWS) as NROWS/2 row-pairs. Results held in regs,
// barrier, in-place writeback to sx/sy.
template <int Y0, int NROWS>
__device__ __forceinline__ void run_phase2(const float* sg, const float* se,
                                           float* sx, float* sy, int tid) {
    constexpr int NU = 18 * (NROWS / 2);
    bool act = tid < NU;
    float ox[2][4], oy[2][4];
    int R0 = 0, ab = 0;
    if (act) {
        int gm = tid % 18, u = tid / 18;
        R0 = Y0 + 2 * u;
        ab = 4 * gm;
        int base = R0 * ST + ab;

        Row rw;
        float cx0[4], cy0[4], ec0[4], cx1[4], cy1[4], ec1[4];
        float xr0[4] = {0.f, 0.f, 0.f, 0.f}, yr0[4] = {0.f, 0.f, 0.f, 0.f};
        float xr1[4] = {0.f, 0.f, 0.f, 0.f}, yr1[4] = {0.f, 0.f, 0.f, 0.f};

        load_row(sg, se, sx, sy, base, rw);           // R0
        extract_center(rw, cx0, cy0, ec0);
        load_row(sg, se, sx, sy, base + ST, rw);      // R1
        extract_center(rw, cx1, cy1, ec1);
        contrib(rw, cx0, cy0, ec0, xr0, yr0);         // R1 -> c0 (dy+1)
        contrib(rw, cx1, cy1, ec1, xr1, yr1);         // R1 -> c1 (dy 0)
        load_row(sg, se, sx, sy, base, rw);           // R0 again
        contrib(rw, cx0, cy0, ec0, xr0, yr0);         // dy 0
        contrib(rw, cx1, cy1, ec1, xr1, yr1);         // dy -1
        load_row(sg, se, sx, sy, base - 2 * ST, rw);  // R0-2
        contrib(rw, cx0, cy0, ec0, xr0, yr0);
        load_row(sg, se, sx, sy, base - ST, rw);      // R0-1
        contrib(rw, cx0, cy0, ec0, xr0, yr0);
        contrib(rw, cx1, cy1, ec1, xr1, yr1);
        load_row(sg, se, sx, sy, base + 2 * ST, rw);  // R1+1
        contrib(rw, cx0, cy0, ec0, xr0, yr0);
        contrib(rw, cx1, cy1, ec1, xr1, yr1);
        load_row(sg, se, sx, sy, base + 3 * ST, rw);  // R1+2
        contrib(rw, cx1, cy1, ec1, xr1, yr1);

#pragma unroll
        for (int k = 0; k < 4; ++k) {
            float i0 = __builtin_amdgcn_rsqf(xr0[k] * xr0[k] + yr0[k] * yr0[k]);
            float i1 = __builtin_amdgcn_rsqf(xr1[k] * xr1[k] + yr1[k] * yr1[k]);
            ox[0][k] = xr0[k] * i0; oy[0][k] = yr0[k] * i0;
            ox[1][k] = xr1[k] * i1; oy[1][k] = yr1[k] * i1;
        }
    }
    __syncthreads();
    if (act) {
#pragma unroll
        for (int rr = 0; rr < 2; ++rr) {
            int c0 = (R0 + rr) * ST + ab + 2;
            *(float2*)&sx[c0] = make_float2(ox[rr][0], ox[rr][1]);
            *(float2*)&sx[c0 + 2] = make_float2(ox[rr][2], ox[rr][3]);
            *(float2*)&sy[c0] = make_float2(oy[rr][0], oy[rr][1]);
            *(float2*)&sy[c0 + 2] = make_float2(oy[rr][2], oy[rr][3]);
        }
    }
    __syncthreads();
}

// K2: all 3 ETF iterations in LDS. Output tile 64x16, staged 76x28 (reflect halo 6).
// Phases 1,2 compute centers cols [2,74) x rows [2,26)/[4,24); phase-2 cols {2,3,72,73}
// are garbage by construction but provably never read by phase 3 (windows [4,72)).
__global__ __launch_bounds__(256) void k_fused3(const float* __restrict__ g,
                                                const float* __restrict__ xin,
                                                const float* __restrict__ yin,
                                                const float* __restrict__ gpart,
                                                float* __restrict__ out,
                                                double* __restrict__ partials) {
    __shared__ __align__(16) float sg[NSTAGE];
    __shared__ __align__(16) float se[NSTAGE];
    __shared__ __align__(16) float sx[NSTAGE];
    __shared__ __align__(16) float sy[NSTAGE];
    __shared__ double swr[8];
    __shared__ float smax_s;

    int ch = blockIdx.z;
    int bx0 = blockIdx.x * 64, by0 = blockIdx.y * 16;
    int tid = threadIdx.x;

    // wave 0: reduce this channel's 256 sobel-block maxima
    if (tid < 64) {
        const float* gp = gpart + ch * 256;
        float m = fmaxf(fmaxf(gp[tid], gp[tid + 64]), fmaxf(gp[tid + 128], gp[tid + 192]));
#pragma unroll
        for (int k = 32; k > 0; k >>= 1) m = fmaxf(m, __shfl_xor(m, k, 64));
        if (tid == 0) smax_s = m;
    }

    // stage g/x/y with reflect halo (cols [bx0-6, bx0+70), rows [by0-6, by0+22))
    const float* gc = g + (size_t)ch * HW;
    const float* xc = xin + (size_t)ch * HW;
    const float* yc = yin + (size_t)ch * HW;
    float vg[9];
#pragma unroll
    for (int j = 0; j < 9; ++j) {
        int i = tid + j * 256;
        if (i < NSTAGE) {
            int r = i / ST, c = i - r * ST;
            int yy = reflect_idx(by0 - 6 + r, H);
            int xx = reflect_idx(bx0 - 6 + c, W);
            int idx = yy * W + xx;
            float gv = gc[idx];
            vg[j] = gv;
            sg[i] = gv;
            sx[i] = xc[idx];
            sy[i] = yc[idx];
        }
    }
    __syncthreads();

    float s2 = -2.f * __builtin_amdgcn_rcpf(smax_s);  // sigmoid(2d/gmax) = 0.5(1+tanh(d/gmax))
#pragma unroll
    for (int j = 0; j < 9; ++j) {
        int i = tid + j * 256;
        if (i < NSTAGE) se[i] = __expf(s2 * vg[j]);
    }
    __syncthreads();

    run_phase2<2, 24>(sg, se, sx, sy, tid);  // iteration 1: rows [2,26)
    run_phase2<4, 20>(sg, se, sx, sy, tid);  // iteration 2: rows [4,24)

    // iteration 3: 256 single-row groups, centers cols [6,70) x rows [6,22),
    // fused with angle + instance-norm partial sums
    double s = 0.0, q = 0.0;
    {
        int gm = tid & 15, gr = tid >> 4;
        int R = 6 + gr;
        int ab = 4 + 4 * gm;          // window [4,76), 16B-aligned
        int base = R * ST + ab;

        Row rw;
        float cx0[4], cy0[4], ec0[4];
        float xr0[4] = {0.f, 0.f, 0.f, 0.f}, yr0[4] = {0.f, 0.f, 0.f, 0.f};

        load_row(sg, se, sx, sy, base, rw);
        extract_center(rw, cx0, cy0, ec0);
        contrib(rw, cx0, cy0, ec0, xr0, yr0);
        load_row(sg, se, sx, sy, base - 2 * ST, rw);
        contrib(rw, cx0, cy0, ec0, xr0, yr0);
        load_row(sg, se, sx, sy, base - ST, rw);
        contrib(rw, cx0, cy0, ec0, xr0, yr0);
        load_row(sg, se, sx, sy, base + ST, rw);
        contrib(rw, cx0, cy0, ec0, xr0, yr0);
        load_row(sg, se, sx, sy, base + 2 * ST, rw);
        contrib(rw, cx0, cy0, ec0, xr0, yr0);

        float a[4];
#pragma unroll
        for (int k = 0; k < 4; ++k) {
            float ang = atanf(-yr0[k] / xr0[k]);  // normalization cancels in the ratio
            a[k] = (180.f * ang) / 3.14159274f;
            s += (double)a[k];
            q += (double)a[k] * (double)a[k];
        }
        float* oc = out + (size_t)ch * HW;
        *(float4*)(oc + (by0 + gr) * W + bx0 + 4 * gm) = make_float4(a[0], a[1], a[2], a[3]);
    }

    // wave shuffle-reduce (64 lanes), then 4 wave-leaders -> thread 0
#pragma unroll
    for (int off = 32; off > 0; off >>= 1) {
        s += __shfl_down(s, off, 64);
        q += __shfl_down(q, off, 64);
    }
    if ((tid & 63) == 0) {
        swr[tid >> 6] = s;
        swr[4 + (tid >> 6)] = q;
    }
    __syncthreads();
    if (tid == 0) {
        double ts = swr[0] + swr[1] + swr[2] + swr[3];
        double tq = swr[4] + swr[5] + swr[6] + swr[7];
        int blk = blockIdx.y * 8 + blockIdx.x;  // 256 blocks per channel
        partials[((size_t)ch * 256 + blk) * 2 + 0] = ts;
        partials[((size_t)ch * 256 + blk) * 2 + 1] = tq;
    }
}

// ---------------- K3: instance norm (inline stats reduce, then normalize) ----------------
__global__ __launch_bounds__(256) void k_norm(float* __restrict__ a,
                                              const double* __restrict__ partials) {
    int ch = blockIdx.y;
    int t = threadIdx.x;

    __shared__ double rs[256], rq[256];
    rs[t] = partials[((size_t)ch * 256 + t) * 2 + 0];
    rq[t] = partials[((size_t)ch * 256 + t) * 2 + 1];
    __syncthreads();
    for (int st = 128; st > 0; st >>= 1) {
        if (t < st) {
            rs[t] += rs[t + st];
            rq[t] += rq[t + st];
        }
        __syncthreads();
    }
    __shared__ float sm, ss;
    if (t == 0) {
        double mean = rs[0] / (double)HW;
        double var = rq[0] / (double)HW - mean * mean;
        sm = (float)mean;
        ss = (float)(1.0 / sqrt(var + 1e-5));
    }
    __syncthreads();
    float mean = sm, sc = ss;

    float4* a4 = (float4*)(a + (size_t)ch * HW + (size_t)blockIdx.x * 4096);
#pragma unroll
    for (int k = 0; k < 4; ++k) {
        float4 v = a4[k * 256 + t];
        v.x = (v.x - mean) * sc;
        v.y = (v.y - mean) * sc;
        v.z = (v.z - mean) * sc;
        v.w = (v.w - mean) * sc;
        a4[k * 256 + t] = v;
    }
}

extern "C" void kernel_launch(void* const* d_in, const int* in_sizes, int n_in,
                              void* d_out, int out_size, void* d_ws, size_t ws_size,
                              hipStream_t stream) {
    (void)in_sizes; (void)n_in; (void)out_size; (void)ws_size;
    const float* img = (const float*)d_in[0];
    float* out = (float*)d_out;

    float* wsf = (float*)d_ws;
    float* gpart = wsf + 512;                       // 6*256
    double* partials = (double*)(wsf + 8192);       // 6*256*2 doubles
    float* g = wsf + 32768;                         // 3 fields of 6 MiB
    float* xnA = g + (size_t)NCH * HW;
    float* ynA = xnA + (size_t)NCH * HW;

    k_sobel<<<dim3(4, 64, NCH), dim3(32, 8), 0, stream>>>(img, gpart, g, xnA, ynA);
    k_fused3<<<dim3(8, 32, NCH), dim3(256), 0, stream>>>(g, xnA, ynA, gpart, out, partials);
    k_norm<<<dim3(64, NCH), dim3(256), 0, stream>>>(out, partials);
}